// Round 4
// baseline (116.885 us; speedup 1.0000x reference)
//
#include <hip/hip_runtime.h>
#include <hip/hip_bf16.h>

// Problem constants (fixed by reference setup_inputs):
//   M=2, L=6, N=512, d=2, H=64;  V_K=1.0, SIGMA=0.1, EPS=1e-10
#define MM 2
#define LL 6
#define NN 512
#define HH 64
#define K_TAB 512
#define RMAX 16.0f
#define H_STEP (RMAX / (float)K_TAB)   // 0.03125
#define HINV   ((float)K_TAB / RMAX)   // 32.0

// ws layout: nodes = float2[K_TAB+1] at offset 0 (phi, h*dphi per node),
//            acc   = float[64]  at byte offset 8192 (48 used),
//            ticket= int        at byte offset 8192+256.
// acc per (m,l): [0]=sum phi, [1]=sum d2phi, [2]=sum ||drift||^2, [3]=sum ||x||^2

__device__ __forceinline__ float wave_reduce_sum(float v) {
    #pragma unroll
    for (int m = 32; m > 0; m >>= 1) v += __shfl_xor(v, m, 64);
    return v;
}

// One wave per table node; lane indexes hidden unit h (and output unit k).
// Also zeroes the accumulators and the last-block ticket counter.
__global__ __launch_bounds__(256) void build_nodes(
        const float* __restrict__ w1, const float* __restrict__ b1,
        const float* __restrict__ W2, const float* __restrict__ b2,
        const float* __restrict__ w3, const float* __restrict__ b3,
        float2* __restrict__ nodes, float* __restrict__ acc,
        int* __restrict__ ticket) {
    int gid  = blockIdx.x * blockDim.x + threadIdx.x;
    int node = gid >> 6;
    int lane = gid & 63;
    if (gid < 64) acc[gid] = 0.0f;   // zero accumulators (48 used)
    if (gid == 64) *ticket = 0;
    if (node > K_TAB) return;        // K_TAB+1 nodes

    float r = (float)node * H_STEP;

    // layer 1 (elementwise in h = lane)
    float w1l = w1[lane];
    float u   = fmaf(r, w1l, b1[lane]);
    float t1  = tanhf(u);
    float e1  = 1.0f - t1 * t1;
    float h1  = t1;
    float h1p = e1 * w1l;            // d h1 / dr

    // layer 2 matvec: v_k = sum_h h1_h * W2[h,k] + b2_k   (k = lane)
    float v = b2[lane], vp = 0.0f;
    #pragma unroll
    for (int h = 0; h < HH; ++h) {
        float a  = __shfl(h1,  h, 64);
        float ap = __shfl(h1p, h, 64);
        float w  = W2[h * HH + lane];
        v  = fmaf(a,  w, v);
        vp = fmaf(ap, w, vp);
    }
    float t2 = tanhf(v);
    float e2 = 1.0f - t2 * t2;
    float w3l = w3[lane];
    float sphi = wave_reduce_sum(w3l * t2);
    float sdp  = wave_reduce_sum(w3l * e2 * vp);
    if (lane == 0)
        nodes[node] = make_float2(sphi + b3[0], sdp * H_STEP);
}

// One wave per particle i; lanes split j. 4 waves (4 i's) per block.
// Block-private cubic-Hermite coeff table in LDS. The LAST block to finish
// (device-scope ticket) performs the final combine -> residual^2.
__global__ __launch_bounds__(256) void pair_kernel(
        const float* __restrict__ data, const float2* __restrict__ nodes,
        const float* __restrict__ t, float* __restrict__ acc,
        int* __restrict__ ticket, float* __restrict__ out) {
    const int blocks_per_ml = NN / 4;
    int ml = blockIdx.x / blocks_per_ml;
    int i4 = blockIdx.x % blocks_per_ml;

    __shared__ float4 coef[K_TAB];   // 8 KB
    __shared__ float2 xs[NN];        // 4 KB
    __shared__ float  red[4 * 4];
    __shared__ bool   is_last;

    // build cubic-Hermite coeffs from node table (L2-broadcast reads)
    #pragma unroll
    for (int it = 0; it < K_TAB / 256; ++it) {
        int e = it * 256 + threadIdx.x;
        float2 g0 = nodes[e];
        float2 g1 = nodes[e + 1];
        float  d  = g1.x - g0.x;
        coef[e] = make_float4(g0.x, g0.y,
                              3.0f * d - 2.0f * g0.y - g1.y,
                              g0.y + g1.y - 2.0f * d);
    }
    // stage the 512 points of this (m,l): 1024 floats = 256 float4
    {
        const float4* src = (const float4*)(data + (size_t)ml * NN * 2);
        ((float4*)xs)[threadIdx.x] = src[threadIdx.x];
    }
    __syncthreads();

    int wv   = threadIdx.x >> 6;
    int lane = threadIdx.x & 63;
    int i    = i4 * 4 + wv;
    float2 xi = xs[i];

    float aphi = 0.0f, ad2 = 0.0f, agx = 0.0f, agy = 0.0f;
    #pragma unroll
    for (int jj = 0; jj < NN / 64; ++jj) {
        int j = jj * 64 + lane;
        float2 xj = xs[j];
        float dx = xi.x - xj.x;
        float dy = xi.y - xj.y;
        float ssq = fmaf(dx, dx, dy * dy);
        float rr  = sqrtf(ssq);
        float f   = rr * HINV;
        int   idx = (int)f;
        idx = idx > (K_TAB - 1) ? (K_TAB - 1) : idx;
        float tt = f - (float)idx;
        float4 c = coef[idx];
        // phi   = c0 + t(c1 + t(c2 + t c3))
        // dphi  = (c1 + t(2c2 + 3c3 t)) / h
        // d2phi = (2c2 + 6c3 t) / h^2
        float phi  = fmaf(tt, fmaf(tt, fmaf(tt, c.w, c.z), c.y), c.x);
        float dph  = fmaf(tt, fmaf(tt, 3.0f * c.w, 2.0f * c.z), c.y) * HINV;
        float d2ph = fmaf(tt, 6.0f * c.w, 2.0f * c.z) * (HINV * HINV);
        float inv_r = 1.0f / fmaxf(rr, 1e-10f);
        bool off = (j != i);
        aphi += off ? phi  : 0.0f;
        ad2  += off ? d2ph : 0.0f;
        // dx=dy=0 when j==i -> gradient terms self-mask
        float s = dph * inv_r;
        agx = fmaf(s, dx, agx);
        agy = fmaf(s, dy, agy);
    }

    aphi = wave_reduce_sum(aphi);
    ad2  = wave_reduce_sum(ad2);
    agx  = wave_reduce_sum(agx);
    agy  = wave_reduce_sum(agy);

    if (lane == 0) {
        const float invN = 1.0f / (float)NN;
        float driftx = -xi.x - agx * invN;   // V_K = 1
        float drifty = -xi.y - agy * invN;
        float dr2 = fmaf(driftx, driftx, drifty * drifty);
        float vsq = fmaf(xi.x, xi.x, xi.y * xi.y);
        red[wv * 4 + 0] = aphi;
        red[wv * 4 + 1] = ad2;
        red[wv * 4 + 2] = dr2;
        red[wv * 4 + 3] = vsq;
    }
    __syncthreads();
    if (threadIdx.x < 4) {
        float s = red[0 * 4 + threadIdx.x] + red[1 * 4 + threadIdx.x]
                + red[2 * 4 + threadIdx.x] + red[3 * 4 + threadIdx.x];
        atomicAdd(&acc[ml * 4 + threadIdx.x], s);
    }

    // ---- last-block finalize (device-scope ticket; no co-residency assumed)
    if (threadIdx.x == 0) {
        __threadfence();   // make this block's atomics visible device-wide
        int prev = __hip_atomic_fetch_add(ticket, 1, __ATOMIC_ACQ_REL,
                                          __HIP_MEMORY_SCOPE_AGENT);
        is_last = (prev == (int)gridDim.x - 1);
    }
    __syncthreads();
    if (is_last && threadIdx.x == 0) {
        const double N = (double)NN;
        const double SIG2 = 0.01;   // SIGMA^2
        const double VKD  = 2.0;    // V_K * d
        double diss = 0.0, diffu = 0.0, dE = 0.0;
        for (int m = 0; m < MM; ++m) {
            double E0 = 0.0;
            for (int l = 0; l < LL; ++l) {
                int idx = m * LL + l;
                // device-scope loads: per-XCD L2 may hold stale lines
                double sphi = (double)__hip_atomic_load(&acc[idx * 4 + 0], __ATOMIC_RELAXED, __HIP_MEMORY_SCOPE_AGENT);
                double sd2  = (double)__hip_atomic_load(&acc[idx * 4 + 1], __ATOMIC_RELAXED, __HIP_MEMORY_SCOPE_AGENT);
                double sdr  = (double)__hip_atomic_load(&acc[idx * 4 + 2], __ATOMIC_RELAXED, __HIP_MEMORY_SCOPE_AGENT);
                double sv   = (double)__hip_atomic_load(&acc[idx * 4 + 3], __ATOMIC_RELAXED, __HIP_MEMORY_SCOPE_AGENT);
                double E = 0.5 * sv / N + sphi / (N * N);
                if (l == 0) E0 = E;
                if (l == LL - 1) dE += E - E0;
                if (l < LL - 1) {
                    double dt = (double)t[l + 1] - (double)t[l];
                    diss  += sdr / N * dt;
                    diffu += SIG2 * (VKD + sd2 / (N * N)) * dt;
                }
            }
        }
        double res = (diss + diffu - 2.0 * dE) / (double)(MM * (LL - 1));
        out[0] = (float)(res * res);
    }
}

extern "C" void kernel_launch(void* const* d_in, const int* in_sizes, int n_in,
                              void* d_out, int out_size, void* d_ws, size_t ws_size,
                              hipStream_t stream) {
    const float* data = (const float*)d_in[0];
    const float* t    = (const float*)d_in[1];
    const float* w1   = (const float*)d_in[2];
    const float* b1   = (const float*)d_in[3];
    const float* W2   = (const float*)d_in[4];
    const float* b2   = (const float*)d_in[5];
    const float* w3   = (const float*)d_in[6];
    const float* b3   = (const float*)d_in[7];

    float2* nodes  = (float2*)d_ws;
    float*  acc    = (float*)((char*)d_ws + 8192);
    int*    ticket = (int*)((char*)d_ws + 8192 + 256);

    // K_TAB+1 = 513 nodes, one wave each -> ceil(513*64/256) = 129 blocks
    build_nodes<<<129, 256, 0, stream>>>(w1, b1, W2, b2, w3, b3, nodes, acc, ticket);
    // 12 (m,l) * 128 blocks = 1536; last block finalizes
    pair_kernel<<<MM * LL * (NN / 4), 256, 0, stream>>>(data, nodes, t, acc, ticket,
                                                        (float*)d_out);
}

// Round 5
// 84.759 us; speedup vs baseline: 1.3790x; 1.3790x over previous
//
#include <hip/hip_runtime.h>
#include <hip/hip_bf16.h>

// Problem constants (fixed by reference setup_inputs):
//   M=2, L=6, N=512, d=2, H=64;  V_K=1.0, SIGMA=0.1, EPS=1e-10
#define MM 2
#define LL 6
#define NN 512
#define HH 64
#define K_TAB 512
#define RMAX 16.0f
#define H_STEP (RMAX / (float)K_TAB)   // 0.03125
#define HINV   ((float)K_TAB / RMAX)   // 32.0
#define NBLK (MM * LL * (NN / 4))      // 1536 pair blocks

// ws layout: nodes   = float2[K_TAB+1] at offset 0,
//            partial = float4[NBLK]    at byte offset 8192.
// partial[b] = (sum phi, sum d2phi, sum ||drift||^2, sum ||x||^2) for that
// block's 4 particles. NO atomics: each block owns its slot (plain store).

__device__ __forceinline__ float wave_reduce_sum(float v) {
    #pragma unroll
    for (int m = 32; m > 0; m >>= 1) v += __shfl_xor(v, m, 64);
    return v;
}

// One wave per table node; lane indexes hidden unit h (and output unit k).
__global__ __launch_bounds__(256) void build_nodes(
        const float* __restrict__ w1, const float* __restrict__ b1,
        const float* __restrict__ W2, const float* __restrict__ b2,
        const float* __restrict__ w3, const float* __restrict__ b3,
        float2* __restrict__ nodes) {
    int gid  = blockIdx.x * blockDim.x + threadIdx.x;
    int node = gid >> 6;
    int lane = gid & 63;
    if (node > K_TAB) return;        // K_TAB+1 nodes

    float r = (float)node * H_STEP;

    // layer 1 (elementwise in h = lane)
    float w1l = w1[lane];
    float u   = fmaf(r, w1l, b1[lane]);
    float t1  = tanhf(u);
    float e1  = 1.0f - t1 * t1;
    float h1  = t1;
    float h1p = e1 * w1l;            // d h1 / dr

    // layer 2 matvec: v_k = sum_h h1_h * W2[h,k] + b2_k   (k = lane)
    float v = b2[lane], vp = 0.0f;
    #pragma unroll
    for (int h = 0; h < HH; ++h) {
        float a  = __shfl(h1,  h, 64);
        float ap = __shfl(h1p, h, 64);
        float w  = W2[h * HH + lane];
        v  = fmaf(a,  w, v);
        vp = fmaf(ap, w, vp);
    }
    float t2 = tanhf(v);
    float e2 = 1.0f - t2 * t2;
    float w3l = w3[lane];
    float sphi = wave_reduce_sum(w3l * t2);
    float sdp  = wave_reduce_sum(w3l * e2 * vp);
    if (lane == 0)
        nodes[node] = make_float2(sphi + b3[0], sdp * H_STEP);
}

// One wave per particle i; lanes split j. 4 waves (4 i's) per block.
// Block-private cubic-Hermite coeff table in LDS; per-block partial stored
// to a private global slot (no atomic contention).
__global__ __launch_bounds__(256) void pair_kernel(
        const float* __restrict__ data, const float2* __restrict__ nodes,
        float4* __restrict__ partial) {
    const int blocks_per_ml = NN / 4;
    int ml = blockIdx.x / blocks_per_ml;
    int i4 = blockIdx.x % blocks_per_ml;

    __shared__ float4 coef[K_TAB];   // 8 KB
    __shared__ float2 xs[NN];        // 4 KB
    __shared__ float  red[4 * 4];

    // build cubic-Hermite coeffs from node table (L2-broadcast reads)
    #pragma unroll
    for (int it = 0; it < K_TAB / 256; ++it) {
        int e = it * 256 + threadIdx.x;
        float2 g0 = nodes[e];
        float2 g1 = nodes[e + 1];
        float  d  = g1.x - g0.x;
        coef[e] = make_float4(g0.x, g0.y,
                              3.0f * d - 2.0f * g0.y - g1.y,
                              g0.y + g1.y - 2.0f * d);
    }
    // stage the 512 points of this (m,l): 1024 floats = 256 float4
    {
        const float4* src = (const float4*)(data + (size_t)ml * NN * 2);
        ((float4*)xs)[threadIdx.x] = src[threadIdx.x];
    }
    __syncthreads();

    int wv   = threadIdx.x >> 6;
    int lane = threadIdx.x & 63;
    int i    = i4 * 4 + wv;
    float2 xi = xs[i];

    float aphi = 0.0f, ad2 = 0.0f, agx = 0.0f, agy = 0.0f;
    #pragma unroll
    for (int jj = 0; jj < NN / 64; ++jj) {
        int j = jj * 64 + lane;
        float2 xj = xs[j];
        float dx = xi.x - xj.x;
        float dy = xi.y - xj.y;
        float ssq = fmaf(dx, dx, dy * dy);
        float rr  = sqrtf(ssq);
        float f   = rr * HINV;
        int   idx = (int)f;
        idx = idx > (K_TAB - 1) ? (K_TAB - 1) : idx;
        float tt = f - (float)idx;
        float4 c = coef[idx];
        // phi   = c0 + t(c1 + t(c2 + t c3))
        // dphi  = (c1 + t(2c2 + 3c3 t)) / h
        // d2phi = (2c2 + 6c3 t) / h^2
        float phi  = fmaf(tt, fmaf(tt, fmaf(tt, c.w, c.z), c.y), c.x);
        float dph  = fmaf(tt, fmaf(tt, 3.0f * c.w, 2.0f * c.z), c.y) * HINV;
        float d2ph = fmaf(tt, 6.0f * c.w, 2.0f * c.z) * (HINV * HINV);
        float inv_r = 1.0f / fmaxf(rr, 1e-10f);
        bool off = (j != i);
        aphi += off ? phi  : 0.0f;
        ad2  += off ? d2ph : 0.0f;
        // dx=dy=0 when j==i -> gradient terms self-mask
        float s = dph * inv_r;
        agx = fmaf(s, dx, agx);
        agy = fmaf(s, dy, agy);
    }

    aphi = wave_reduce_sum(aphi);
    ad2  = wave_reduce_sum(ad2);
    agx  = wave_reduce_sum(agx);
    agy  = wave_reduce_sum(agy);

    if (lane == 0) {
        const float invN = 1.0f / (float)NN;
        float driftx = -xi.x - agx * invN;   // V_K = 1
        float drifty = -xi.y - agy * invN;
        float dr2 = fmaf(driftx, driftx, drifty * drifty);
        float vsq = fmaf(xi.x, xi.x, xi.y * xi.y);
        red[wv * 4 + 0] = aphi;
        red[wv * 4 + 1] = ad2;
        red[wv * 4 + 2] = dr2;
        red[wv * 4 + 3] = vsq;
    }
    __syncthreads();
    if (threadIdx.x == 0) {
        partial[blockIdx.x] = make_float4(
            red[0] + red[4] + red[8]  + red[12],
            red[1] + red[5] + red[9]  + red[13],
            red[2] + red[6] + red[10] + red[14],
            red[3] + red[7] + red[11] + red[15]);
    }
}

// One block. Threads [0,48): (ml,stat) pair sums its 128 block-partials,
// then thread 0 combines in fp64.
__global__ __launch_bounds__(64) void finalize(
        const float* __restrict__ partial, const float* __restrict__ t,
        float* __restrict__ out) {
    __shared__ float sums[48];
    int tid = threadIdx.x;
    if (tid < 48) {
        int ml   = tid >> 2;
        int stat = tid & 3;
        const float* p = partial + (size_t)ml * (NN / 4) * 4 + stat;
        float s = 0.0f;
        #pragma unroll 8
        for (int b = 0; b < NN / 4; ++b) s += p[b * 4];
        sums[tid] = s;
    }
    __syncthreads();
    if (tid == 0) {
        const double N = (double)NN;
        const double SIG2 = 0.01;   // SIGMA^2
        const double VKD  = 2.0;    // V_K * d
        double diss = 0.0, diffu = 0.0, dE = 0.0;
        for (int m = 0; m < MM; ++m) {
            double E0 = 0.0;
            for (int l = 0; l < LL; ++l) {
                int idx = m * LL + l;
                double sphi = (double)sums[idx * 4 + 0];
                double sd2  = (double)sums[idx * 4 + 1];
                double sdr  = (double)sums[idx * 4 + 2];
                double sv   = (double)sums[idx * 4 + 3];
                double E = 0.5 * sv / N + sphi / (N * N);
                if (l == 0) E0 = E;
                if (l == LL - 1) dE += E - E0;
                if (l < LL - 1) {
                    double dt = (double)t[l + 1] - (double)t[l];
                    diss  += sdr / N * dt;
                    diffu += SIG2 * (VKD + sd2 / (N * N)) * dt;
                }
            }
        }
        double res = (diss + diffu - 2.0 * dE) / (double)(MM * (LL - 1));
        out[0] = (float)(res * res);
    }
}

extern "C" void kernel_launch(void* const* d_in, const int* in_sizes, int n_in,
                              void* d_out, int out_size, void* d_ws, size_t ws_size,
                              hipStream_t stream) {
    const float* data = (const float*)d_in[0];
    const float* t    = (const float*)d_in[1];
    const float* w1   = (const float*)d_in[2];
    const float* b1   = (const float*)d_in[3];
    const float* W2   = (const float*)d_in[4];
    const float* b2   = (const float*)d_in[5];
    const float* w3   = (const float*)d_in[6];
    const float* b3   = (const float*)d_in[7];

    float2* nodes   = (float2*)d_ws;
    float4* partial = (float4*)((char*)d_ws + 8192);

    // K_TAB+1 = 513 nodes, one wave each -> 129 blocks of 4 waves
    build_nodes<<<129, 256, 0, stream>>>(w1, b1, W2, b2, w3, b3, nodes);
    // 12 (m,l) * 128 blocks = 1536; per-block private partial slot
    pair_kernel<<<NBLK, 256, 0, stream>>>(data, nodes, partial);
    finalize<<<1, 64, 0, stream>>>((const float*)partial, t, (float*)d_out);
}